// Round 1
// baseline (3938.799 us; speedup 1.0000x reference)
//
#include <hip/hip_runtime.h>
#include <hip/hip_bf16.h>
#include <stdint.h>

#define B_   8192
#define IN_  2048
#define H0_  1024
#define H1_  512
#define D_   256
#define Q_   8
#define K_   2048

// ---------------- fp32 tiled GEMM: C = act(A @ W + bias) ----------------
// A: M x K row-major, W: K x N row-major, bias: N, C: M x N row-major.
// BM=BN=128, BK=16, 256 threads, 8x8 register tile per thread.
template<int RELU>
__global__ __launch_bounds__(256)
void gemm_bias_kernel(const float* __restrict__ A, const float* __restrict__ W,
                      const float* __restrict__ bias, float* __restrict__ C,
                      int M, int N, int Kd)
{
    const int BM = 128, BN = 128, BK = 16, TM = 8, TN = 8;
    __shared__ float As[BK][BM];
    __shared__ float Bs[BK][BN];

    const int tid = threadIdx.x;
    const int tx = tid & 15;        // n-dir (16)
    const int ty = tid >> 4;        // m-dir (16)
    const int row0 = blockIdx.y * BM;
    const int col0 = blockIdx.x * BN;

    float acc[TM][TN];
#pragma unroll
    for (int i = 0; i < TM; i++)
#pragma unroll
        for (int j = 0; j < TN; j++) acc[i][j] = 0.f;

    const int a_row = tid >> 2;         // 0..63
    const int a_col = (tid & 3) * 4;    // 0,4,8,12
    const int b_row = tid >> 5;         // 0..7
    const int b_col = (tid & 31) * 4;   // 0..124

    for (int k0 = 0; k0 < Kd; k0 += BK) {
        // A tile (128 x 16) -> transposed into As[k][m]
#pragma unroll
        for (int r = 0; r < 2; r++) {
            int m = a_row + r * 64;
            float4 v = *(const float4*)(&A[(size_t)(row0 + m) * Kd + k0 + a_col]);
            As[a_col + 0][m] = v.x;
            As[a_col + 1][m] = v.y;
            As[a_col + 2][m] = v.z;
            As[a_col + 3][m] = v.w;
        }
        // W tile (16 x 128) -> Bs[k][n] direct
#pragma unroll
        for (int r = 0; r < 2; r++) {
            int k = b_row + r * 8;
            float4 v = *(const float4*)(&W[(size_t)(k0 + k) * N + col0 + b_col]);
            *(float4*)(&Bs[k][b_col]) = v;
        }
        __syncthreads();
#pragma unroll
        for (int kk = 0; kk < BK; kk++) {
            float a[TM], b[TN];
#pragma unroll
            for (int i = 0; i < TM; i++) a[i] = As[kk][ty * TM + i];
#pragma unroll
            for (int j = 0; j < TN; j++) b[j] = Bs[kk][tx * TN + j];
#pragma unroll
            for (int i = 0; i < TM; i++)
#pragma unroll
                for (int j = 0; j < TN; j++)
                    acc[i][j] = fmaf(a[i], b[j], acc[i][j]);
        }
        __syncthreads();
    }

#pragma unroll
    for (int i = 0; i < TM; i++) {
        int m = row0 + ty * TM + i;
#pragma unroll
        for (int j = 0; j < TN; j += 4) {
            int n = col0 + tx * TN + j;
            float4 o;
            o.x = acc[i][j + 0] + bias[n + 0];
            o.y = acc[i][j + 1] + bias[n + 1];
            o.z = acc[i][j + 2] + bias[n + 2];
            o.w = acc[i][j + 3] + bias[n + 3];
            if (RELU) {
                o.x = fmaxf(o.x, 0.f); o.y = fmaxf(o.y, 0.f);
                o.z = fmaxf(o.z, 0.f); o.w = fmaxf(o.w, 0.f);
            }
            *(float4*)(&C[(size_t)m * N + n]) = o;
        }
    }
}

// ---------------- VQ: distance GEMM + fused argmin ----------------
__device__ __forceinline__ unsigned fkey(float f) {
    unsigned u = __float_as_uint(f);
    return (u & 0x80000000u) ? ~u : (u | 0x80000000u);
}

// R: B x D residuals; CB: K x D codebook (one stage); cnorm: K precomputed ||c||^2.
// dist = cnorm[n] - 2 * (r . c)   (||r||^2 omitted: constant per row for argmin)
__global__ __launch_bounds__(256)
void dist_argmin_kernel(const float* __restrict__ R, const float* __restrict__ CB,
                        const float* __restrict__ cnorm,
                        unsigned long long* __restrict__ best)
{
    const int BM = 128, BN = 128, BK = 16, TM = 8, TN = 8;
    __shared__ float As[BK][BM];
    __shared__ float Bs[BK][BN];

    const int tid = threadIdx.x;
    const int tx = tid & 15;
    const int ty = tid >> 4;
    const int row0 = blockIdx.y * BM;
    const int col0 = blockIdx.x * BN;

    float acc[TM][TN];
#pragma unroll
    for (int i = 0; i < TM; i++)
#pragma unroll
        for (int j = 0; j < TN; j++) acc[i][j] = 0.f;

    const int a_row = tid >> 2;
    const int a_col = (tid & 3) * 4;

    for (int k0 = 0; k0 < D_; k0 += BK) {
#pragma unroll
        for (int r = 0; r < 2; r++) {
            int m = a_row + r * 64;
            float4 v = *(const float4*)(&R[(size_t)(row0 + m) * D_ + k0 + a_col]);
            As[a_col + 0][m] = v.x;
            As[a_col + 1][m] = v.y;
            As[a_col + 2][m] = v.z;
            As[a_col + 3][m] = v.w;
        }
        // codebook rows are the "columns": Bs[k][n] = CB[(col0+n)*D + k0+k]
#pragma unroll
        for (int r = 0; r < 2; r++) {
            int n = a_row + r * 64;
            float4 v = *(const float4*)(&CB[(size_t)(col0 + n) * D_ + k0 + a_col]);
            Bs[a_col + 0][n] = v.x;
            Bs[a_col + 1][n] = v.y;
            Bs[a_col + 2][n] = v.z;
            Bs[a_col + 3][n] = v.w;
        }
        __syncthreads();
#pragma unroll
        for (int kk = 0; kk < BK; kk++) {
            float a[TM], b[TN];
#pragma unroll
            for (int i = 0; i < TM; i++) a[i] = As[kk][ty * TM + i];
#pragma unroll
            for (int j = 0; j < TN; j++) b[j] = Bs[kk][tx * TN + j];
#pragma unroll
            for (int i = 0; i < TM; i++)
#pragma unroll
                for (int j = 0; j < TN; j++)
                    acc[i][j] = fmaf(a[i], b[j], acc[i][j]);
        }
        __syncthreads();
    }

    // per-thread argmin over its 8 columns, then global atomicMin per row
#pragma unroll
    for (int i = 0; i < TM; i++) {
        int m = row0 + ty * TM + i;
        float bd = 3.4e38f;
        int bn = 0;
#pragma unroll
        for (int j = 0; j < TN; j++) {
            int n = col0 + tx * TN + j;
            float dd = cnorm[n] - 2.0f * acc[i][j];
            if (dd < bd) { bd = dd; bn = n; }
        }
        unsigned long long p = ((unsigned long long)fkey(bd) << 32) | (unsigned)bn;
        atomicMin(&best[m], p);
    }
}

// one wave per row: gather codeword, loss, residual/quant update, write index
__global__ __launch_bounds__(256)
void vq_update_kernel(const unsigned long long* __restrict__ best,
                      const float* __restrict__ CB,
                      float* __restrict__ resid, float* __restrict__ quant,
                      float* __restrict__ out_idx, float* __restrict__ loss_acc,
                      int q)
{
    const int lane = threadIdx.x & 63;
    const int w = threadIdx.x >> 6;
    const int m = blockIdx.x * 4 + w;
    const unsigned idx = (unsigned)(best[m] & 0xffffffffu);

    const float4 cv = *(const float4*)(&CB[(size_t)idx * D_ + lane * 4]);
    float4 rv = *(const float4*)(&resid[(size_t)m * D_ + lane * 4]);
    float4 qv = *(const float4*)(&quant[(size_t)m * D_ + lane * 4]);

    float dx = rv.x - cv.x, dy = rv.y - cv.y, dz = rv.z - cv.z, dw = rv.w - cv.w;
    float ls = dx * dx + dy * dy + dz * dz + dw * dw;

    qv.x += cv.x; qv.y += cv.y; qv.z += cv.z; qv.w += cv.w;
    *(float4*)(&quant[(size_t)m * D_ + lane * 4]) = qv;
    rv.x = dx; rv.y = dy; rv.z = dz; rv.w = dw;
    *(float4*)(&resid[(size_t)m * D_ + lane * 4]) = rv;

#pragma unroll
    for (int o = 32; o > 0; o >>= 1) ls += __shfl_down(ls, o, 64);
    if (lane == 0) {
        atomicAdd(&loss_acc[q], ls);
        out_idx[(size_t)m * Q_ + q] = (float)idx;
    }
}

// ---------------- small helpers ----------------
__global__ void cnorm_kernel(const float* __restrict__ cb, float* __restrict__ cn)
{
    const int lane = threadIdx.x & 63;
    const int w = threadIdx.x >> 6;
    const int row = blockIdx.x * 4 + w;  // Q_*K_ rows
    const float4 v = *(const float4*)(&cb[(size_t)row * D_ + lane * 4]);
    float s = v.x * v.x + v.y * v.y + v.z * v.z + v.w * v.w;
#pragma unroll
    for (int o = 32; o > 0; o >>= 1) s += __shfl_down(s, o, 64);
    if (lane == 0) cn[row] = s;
}

__global__ void rvq_init_kernel(const float* __restrict__ z,
                                float* __restrict__ quant, float* __restrict__ resid,
                                float* __restrict__ loss_acc)
{
    int i = blockIdx.x * blockDim.x + threadIdx.x;   // over B_*D_/4
    float4 zv = ((const float4*)z)[i];
    ((float4*)quant)[i] = make_float4(0.f, 0.f, 0.f, 0.f);
    ((float4*)resid)[i] = zv;
    if (i < Q_) loss_acc[i] = 0.f;
}

__global__ void init_best_kernel(unsigned long long* __restrict__ best)
{
    int i = blockIdx.x * blockDim.x + threadIdx.x;
    best[i] = ~0ull;
}

__global__ void loss_write_kernel(const float* __restrict__ loss_acc,
                                  float* __restrict__ out_loss)
{
    int q = threadIdx.x;
    if (q < Q_) out_loss[q] = loss_acc[q] * (1.0f / ((float)B_ * (float)D_));
}

// ---------------- launch ----------------
extern "C" void kernel_launch(void* const* d_in, const int* in_sizes, int n_in,
                              void* d_out, int out_size, void* d_ws, size_t ws_size,
                              hipStream_t stream)
{
    const float* x    = (const float*)d_in[0];
    const float* e_w0 = (const float*)d_in[1];
    const float* e_b0 = (const float*)d_in[2];
    const float* e_w1 = (const float*)d_in[3];
    const float* e_b1 = (const float*)d_in[4];
    const float* e_w2 = (const float*)d_in[5];
    const float* e_b2 = (const float*)d_in[6];
    const float* d_w0 = (const float*)d_in[7];
    const float* d_b0 = (const float*)d_in[8];
    const float* d_w1 = (const float*)d_in[9];
    const float* d_b1 = (const float*)d_in[10];
    const float* d_w2 = (const float*)d_in[11];
    const float* d_b2 = (const float*)d_in[12];
    const float* codebooks = (const float*)d_in[13];

    float* out = (float*)d_out;
    float* out_decoded = out;                       // B_*IN_
    float* out_idx     = out + (size_t)B_ * IN_;    // B_*Q_ (as floats)
    float* out_loss    = out_idx + (size_t)B_ * Q_; // Q_

    // workspace carve-up (floats)
    float* ws = (float*)d_ws;
    float* h0    = ws;                          // B_*H0_
    float* h1    = h0 + (size_t)B_ * H0_;       // B_*H1_
    float* z     = h1 + (size_t)B_ * H1_;       // B_*D_
    float* quant = z  + (size_t)B_ * D_;        // B_*D_
    float* resid = quant + (size_t)B_ * D_;     // B_*D_
    float* cnorm = resid + (size_t)B_ * D_;     // Q_*K_
    float* loss  = cnorm + (size_t)Q_ * K_;     // 16 (8 used, keep alignment)
    unsigned long long* best = (unsigned long long*)(loss + 16); // B_

    // ---- encoder ----
    gemm_bias_kernel<1><<<dim3(H0_ / 128, B_ / 128), 256, 0, stream>>>(
        x, e_w0, e_b0, h0, B_, H0_, IN_);
    gemm_bias_kernel<1><<<dim3(H1_ / 128, B_ / 128), 256, 0, stream>>>(
        h0, e_w1, e_b1, h1, B_, H1_, H0_);
    gemm_bias_kernel<0><<<dim3(D_ / 128, B_ / 128), 256, 0, stream>>>(
        h1, e_w2, e_b2, z, B_, D_, H1_);

    // ---- residual VQ ----
    cnorm_kernel<<<(Q_ * K_) / 4, 256, 0, stream>>>(codebooks, cnorm);
    rvq_init_kernel<<<(B_ * D_ / 4) / 256, 256, 0, stream>>>(z, quant, resid, loss);

    for (int q = 0; q < Q_; q++) {
        const float* cb_q = codebooks + (size_t)q * K_ * D_;
        init_best_kernel<<<B_ / 256, 256, 0, stream>>>(best);
        dist_argmin_kernel<<<dim3(K_ / 128, B_ / 128), 256, 0, stream>>>(
            resid, cb_q, cnorm + (size_t)q * K_, best);
        vq_update_kernel<<<B_ / 4, 256, 0, stream>>>(
            best, cb_q, resid, quant, out_idx, loss, q);
    }
    loss_write_kernel<<<1, 64, 0, stream>>>(loss, out_loss);

    // ---- decoder (reuse h1/h0 buffers) ----
    gemm_bias_kernel<1><<<dim3(H1_ / 128, B_ / 128), 256, 0, stream>>>(
        quant, d_w0, d_b0, h1, B_, H1_, D_);
    gemm_bias_kernel<1><<<dim3(H0_ / 128, B_ / 128), 256, 0, stream>>>(
        h1, d_w1, d_b1, h0, B_, H0_, H1_);
    gemm_bias_kernel<0><<<dim3(IN_ / 128, B_ / 128), 256, 0, stream>>>(
        h0, d_w2, d_b2, out_decoded, B_, IN_, H0_);
}

// Round 4
// 1784.733 us; speedup vs baseline: 2.2069x; 2.2069x over previous
//
#include <hip/hip_runtime.h>
#include <stdint.h>

#define B_   8192
#define IN_  2048
#define H0_  1024
#define H1_  512
#define D_   256
#define Q_   8
#define K_   2048

typedef unsigned long long u64;
typedef unsigned short u16;
typedef __attribute__((ext_vector_type(8))) short bf16x8;
typedef __attribute__((ext_vector_type(4))) float f32x4;

__device__ __forceinline__ u16 f2bf(float x) {
    unsigned u = __float_as_uint(x);
    return (u16)((u + 0x7fffu + ((u >> 16) & 1u)) >> 16);
}
__device__ __forceinline__ float bf2f(u16 h) {
    return __uint_as_float((unsigned)h << 16);
}
__device__ __forceinline__ void gload_lds16(const void* g, void* l) {
    __builtin_amdgcn_global_load_lds(
        (const __attribute__((address_space(1))) void*)g,
        (__attribute__((address_space(3))) void*)l, 16, 0, 0);
}
__device__ __forceinline__ unsigned fkey(float f) {
    unsigned u = __float_as_uint(f);
    return (u & 0x80000000u) ? ~u : (u | 0x80000000u);
}

// =====================================================================
// MFMA GEMM: C = act(A @ Bt^T + bias)  or  DIST(argmin) epilogue.
// A: M x Kd fp32 row-major, split into NS bf16 planes during staging.
// Bt: NS pre-split bf16 arrays, N x Kd row-major (i.e. B transposed).
// Tile 128x128, BK=32, 4 waves (2x2), 16x16x32 MFMA, 4x4 frags/wave.
// LDS XOR-swizzle: phys = (row*64 + kbyte) ^ ((row&7)<<4); B staged via
// global_load_lds with inverse-swizzled global source (linear LDS dest).
// =====================================================================
template<int NS, int RELU, int DIST>
__global__ __launch_bounds__(256)
void gemm_mfma(const float* __restrict__ A,
               const u16* __restrict__ Bt0, const u16* __restrict__ Bt1,
               const u16* __restrict__ Bt2,
               const float* __restrict__ bias,   // bias (MLP) or cnorm (DIST)
               float* __restrict__ C,
               u64* __restrict__ best,
               int M, int N, int Kd)
{
    __shared__ __align__(16) char smem[NS * 16384];   // NS*(8KB A + 8KB B)
    const int tid  = threadIdx.x;
    const int lane = tid & 63;
    const int wid  = tid >> 6;
    const int wr   = wid >> 1, wc = wid & 1;
    const int row0 = blockIdx.y * 128;
    const int col0 = blockIdx.x * 128;

    // ---- A staging map: thread -> (row, k-half) ----
    const int ar = tid >> 1;            // 0..127
    const int ah = tid & 1;             // 0/1 -> k 0..15 / 16..31
    const float* ap = A + (size_t)(row0 + ar) * Kd + ah * 16;

    // ---- B staging map: inverse swizzle per 16B chunk ----
    const u16* bsrc[3][2];
#pragma unroll
    for (int h = 0; h < 2; h++) {
        int ch  = h * 256 + wid * 64 + lane;                 // linear 16B chunk
        int row = ((ch >> 3) << 1) | (((ch >> 2) & 1) ^ ((ch >> 4) & 1));
        int kc  = (ch & 3) ^ (row & 3);
        size_t off = (size_t)(col0 + row) * Kd + kc * 8;
        bsrc[0][h] = Bt0 + off;
        if constexpr (NS >= 2) bsrc[1][h] = Bt1 + off;
        if constexpr (NS >= 3) bsrc[2][h] = Bt2 + off;
    }

    f32x4 acc[4][4];
#pragma unroll
    for (int m = 0; m < 4; m++)
#pragma unroll
        for (int n = 0; n < 4; n++) acc[m][n] = (f32x4){0.f, 0.f, 0.f, 0.f};

    // fragment read offset (swizzled), lane-constant
    const unsigned fro = (unsigned)((((lane & 15) * 64 + (lane >> 4) * 16)
                                     ^ ((lane & 7) << 4)));

    for (int k0 = 0; k0 < Kd; k0 += 32) {
        // ---- B tiles: async global->LDS (linear dest, preswizzled src) ----
#pragma unroll
        for (int s = 0; s < NS; s++)
#pragma unroll
            for (int h = 0; h < 2; h++) {
                gload_lds16(bsrc[s][h],
                            smem + NS * 8192 + s * 8192 + (h * 256 + wid * 64) * 16);
                bsrc[s][h] += 32;
            }
        // ---- A tile: fp32 load -> NS bf16 splits -> swizzled ds_write ----
        float4 f0 = *(const float4*)(ap + 0);
        float4 f1 = *(const float4*)(ap + 4);
        float4 f2 = *(const float4*)(ap + 8);
        float4 f3 = *(const float4*)(ap + 12);
        ap += 32;
        float vv[16] = {f0.x, f0.y, f0.z, f0.w, f1.x, f1.y, f1.z, f1.w,
                        f2.x, f2.y, f2.z, f2.w, f3.x, f3.y, f3.z, f3.w};
#pragma unroll
        for (int q = 0; q < 4; q++) {
            const unsigned wb =
                (unsigned)((ar * 64 + ah * 32 + q * 8) ^ ((ar & 7) << 4));
            u16 h4[4], m4[4], l4[4];
#pragma unroll
            for (int e = 0; e < 4; e++) {
                float x = vv[q * 4 + e];
                h4[e] = f2bf(x);
                if constexpr (NS >= 2) {
                    float r1 = x - bf2f(h4[e]);
                    m4[e] = f2bf(r1);
                    if constexpr (NS >= 3) { r1 -= bf2f(m4[e]); l4[e] = f2bf(r1); }
                }
            }
            *(ushort4*)(smem + wb) = make_ushort4(h4[0], h4[1], h4[2], h4[3]);
            if constexpr (NS >= 2)
                *(ushort4*)(smem + 8192 + wb) = make_ushort4(m4[0], m4[1], m4[2], m4[3]);
            if constexpr (NS >= 3)
                *(ushort4*)(smem + 16384 + wb) = make_ushort4(l4[0], l4[1], l4[2], l4[3]);
        }
        __syncthreads();

        // ---- compute ----
        bf16x8 bfr[4][3];
#pragma unroll
        for (int n = 0; n < 4; n++)
#pragma unroll
            for (int s = 0; s < NS; s++)
                bfr[n][s] = *(const bf16x8*)(smem + NS * 8192 + s * 8192
                                             + (wc * 64 + n * 16) * 64 + fro);
#pragma unroll
        for (int m = 0; m < 4; m++) {
            bf16x8 af[3];
#pragma unroll
            for (int s = 0; s < NS; s++)
                af[s] = *(const bf16x8*)(smem + s * 8192
                                         + (wr * 64 + m * 16) * 64 + fro);
#pragma unroll
            for (int n = 0; n < 4; n++) {
                acc[m][n] = __builtin_amdgcn_mfma_f32_16x16x32_bf16(af[0], bfr[n][0], acc[m][n], 0, 0, 0);
                if constexpr (NS >= 2) {
                    acc[m][n] = __builtin_amdgcn_mfma_f32_16x16x32_bf16(af[1], bfr[n][0], acc[m][n], 0, 0, 0);
                    acc[m][n] = __builtin_amdgcn_mfma_f32_16x16x32_bf16(af[0], bfr[n][1], acc[m][n], 0, 0, 0);
                    acc[m][n] = __builtin_amdgcn_mfma_f32_16x16x32_bf16(af[1], bfr[n][1], acc[m][n], 0, 0, 0);
                }
                if constexpr (NS >= 3) {
                    acc[m][n] = __builtin_amdgcn_mfma_f32_16x16x32_bf16(af[2], bfr[n][0], acc[m][n], 0, 0, 0);
                    acc[m][n] = __builtin_amdgcn_mfma_f32_16x16x32_bf16(af[0], bfr[n][2], acc[m][n], 0, 0, 0);
                }
            }
        }
        __syncthreads();
    }

    // ---- epilogue ----
    // C/D layout (verified m89/m91): col = lane&15, row = (lane>>4)*4 + reg
    const int rbase = row0 + wr * 64 + (lane >> 4) * 4;
    const int cbase = col0 + wc * 64 + (lane & 15);

    if constexpr (DIST) {
        float cn[4];
#pragma unroll
        for (int n = 0; n < 4; n++) cn[n] = bias[cbase + n * 16];
#pragma unroll
        for (int m = 0; m < 4; m++)
#pragma unroll
            for (int r = 0; r < 4; r++) {
                float bd = cn[0] - 2.0f * acc[m][0][r];
                int   bc = cbase;
#pragma unroll
                for (int n = 1; n < 4; n++) {
                    float dd = cn[n] - 2.0f * acc[m][n][r];
                    if (dd < bd) { bd = dd; bc = cbase + n * 16; }
                }
                u64 p = ((u64)fkey(bd) << 32) | (unsigned)bc;
#pragma unroll
                for (int msk = 1; msk <= 8; msk <<= 1) {
                    u64 o = __shfl_xor(p, msk, 64);
                    if (o < p) p = o;
                }
                if ((lane & 15) == 0)
                    atomicMin(&best[rbase + m * 16 + r], p);
            }
    } else {
        float bv[4];
#pragma unroll
        for (int n = 0; n < 4; n++) bv[n] = bias[cbase + n * 16];
#pragma unroll
        for (int m = 0; m < 4; m++)
#pragma unroll
            for (int n = 0; n < 4; n++)
#pragma unroll
                for (int r = 0; r < 4; r++) {
                    float o = acc[m][n][r] + bv[n];
                    if (RELU) o = fmaxf(o, 0.f);
                    C[(size_t)(rbase + m * 16 + r) * N + (cbase + n * 16)] = o;
                }
    }
}

// ---------------- weight transpose + split prepass ----------------
template<int NS>
__global__ __launch_bounds__(256)
void wsplit_kernel(const float* __restrict__ W, u16* __restrict__ T0,
                   u16* __restrict__ T1, u16* __restrict__ T2, int Kd, int N)
{
    __shared__ float t[32][33];
    const int tx = threadIdx.x & 31, ty = threadIdx.x >> 5;
    const int n0 = blockIdx.x * 32, k0 = blockIdx.y * 32;
#pragma unroll
    for (int r = 0; r < 4; r++)
        t[ty + r * 8][tx] = W[(size_t)(k0 + ty + r * 8) * N + n0 + tx];
    __syncthreads();
#pragma unroll
    for (int r = 0; r < 4; r++) {
        int n = n0 + ty + r * 8, k = k0 + tx;
        float v = t[tx][ty + r * 8];
        u16 h = f2bf(v);
        T0[(size_t)n * Kd + k] = h;
        if constexpr (NS >= 2) {
            float rr = v - bf2f(h);
            u16 m = f2bf(rr);
            T1[(size_t)n * Kd + k] = m;
            if constexpr (NS >= 3) { rr -= bf2f(m); T2[(size_t)n * Kd + k] = f2bf(rr); }
        }
    }
}

// ---------------- codebook split (no transpose needed) ----------------
__global__ __launch_bounds__(256)
void cbsplit_kernel(const float* __restrict__ cb, u16* __restrict__ s0,
                    u16* __restrict__ s1, u16* __restrict__ s2)
{
    int i = blockIdx.x * 256 + threadIdx.x;   // over Q_*K_*D_/4
    float4 v = ((const float4*)cb)[i];
    float x[4] = {v.x, v.y, v.z, v.w};
    u16 h[4], m[4], l[4];
#pragma unroll
    for (int e = 0; e < 4; e++) {
        h[e] = f2bf(x[e]);
        float r1 = x[e] - bf2f(h[e]);
        m[e] = f2bf(r1);
        r1 -= bf2f(m[e]);
        l[e] = f2bf(r1);
    }
    ((ushort4*)s0)[i] = make_ushort4(h[0], h[1], h[2], h[3]);
    ((ushort4*)s1)[i] = make_ushort4(m[0], m[1], m[2], m[3]);
    ((ushort4*)s2)[i] = make_ushort4(l[0], l[1], l[2], l[3]);
}

// ---------------- VQ helpers ----------------
__global__ __launch_bounds__(256)
void vq_update_kernel(const u64* __restrict__ best,
                      const float* __restrict__ CB,
                      float* __restrict__ resid, float* __restrict__ quant,
                      float* __restrict__ out_idx, float* __restrict__ loss_acc,
                      int q)
{
    const int lane = threadIdx.x & 63;
    const int w = threadIdx.x >> 6;
    const int m = blockIdx.x * 4 + w;
    const unsigned idx = (unsigned)(best[m] & 0xffffffffu);

    const float4 cv = *(const float4*)(&CB[(size_t)idx * D_ + lane * 4]);
    float4 rv = *(const float4*)(&resid[(size_t)m * D_ + lane * 4]);
    float4 qv = *(const float4*)(&quant[(size_t)m * D_ + lane * 4]);

    float dx = rv.x - cv.x, dy = rv.y - cv.y, dz = rv.z - cv.z, dw = rv.w - cv.w;
    float ls = dx * dx + dy * dy + dz * dz + dw * dw;

    qv.x += cv.x; qv.y += cv.y; qv.z += cv.z; qv.w += cv.w;
    *(float4*)(&quant[(size_t)m * D_ + lane * 4]) = qv;
    rv.x = dx; rv.y = dy; rv.z = dz; rv.w = dw;
    *(float4*)(&resid[(size_t)m * D_ + lane * 4]) = rv;

#pragma unroll
    for (int o = 32; o > 0; o >>= 1) ls += __shfl_down(ls, o, 64);
    if (lane == 0) {
        atomicAdd(&loss_acc[q], ls);
        out_idx[(size_t)m * Q_ + q] = (float)idx;
    }
}

__global__ void cnorm_kernel(const float* __restrict__ cb, float* __restrict__ cn)
{
    const int lane = threadIdx.x & 63;
    const int w = threadIdx.x >> 6;
    const int row = blockIdx.x * 4 + w;
    const float4 v = *(const float4*)(&cb[(size_t)row * D_ + lane * 4]);
    float s = v.x * v.x + v.y * v.y + v.z * v.z + v.w * v.w;
#pragma unroll
    for (int o = 32; o > 0; o >>= 1) s += __shfl_down(s, o, 64);
    if (lane == 0) cn[row] = s;
}

__global__ void rvq_init_kernel(const float* __restrict__ z,
                                float* __restrict__ quant, float* __restrict__ resid,
                                float* __restrict__ loss_acc)
{
    int i = blockIdx.x * blockDim.x + threadIdx.x;
    float4 zv = ((const float4*)z)[i];
    ((float4*)quant)[i] = make_float4(0.f, 0.f, 0.f, 0.f);
    ((float4*)resid)[i] = zv;
    if (i < Q_) loss_acc[i] = 0.f;
}

__global__ void init_best_kernel(u64* __restrict__ best)
{
    int i = blockIdx.x * blockDim.x + threadIdx.x;
    best[i] = ~0ull;
}

__global__ void loss_write_kernel(const float* __restrict__ loss_acc,
                                  float* __restrict__ out_loss)
{
    int q = threadIdx.x;
    if (q < Q_) out_loss[q] = loss_acc[q] * (1.0f / ((float)B_ * (float)D_));
}

// ---------------- launch ----------------
extern "C" void kernel_launch(void* const* d_in, const int* in_sizes, int n_in,
                              void* d_out, int out_size, void* d_ws, size_t ws_size,
                              hipStream_t stream)
{
    const float* x    = (const float*)d_in[0];
    const float* e_w0 = (const float*)d_in[1];
    const float* e_b0 = (const float*)d_in[2];
    const float* e_w1 = (const float*)d_in[3];
    const float* e_b1 = (const float*)d_in[4];
    const float* e_w2 = (const float*)d_in[5];
    const float* e_b2 = (const float*)d_in[6];
    const float* d_w0 = (const float*)d_in[7];
    const float* d_b0 = (const float*)d_in[8];
    const float* d_w1 = (const float*)d_in[9];
    const float* d_b1 = (const float*)d_in[10];
    const float* d_w2 = (const float*)d_in[11];
    const float* d_b2 = (const float*)d_in[12];
    const float* codebooks = (const float*)d_in[13];

    float* out = (float*)d_out;
    float* out_decoded = out;                        // B_*IN_
    float* out_idx     = out + (size_t)B_ * IN_;     // B_*Q_
    float* out_loss    = out_idx + (size_t)B_ * Q_;  // Q_

    // ---- workspace carve-up ----
    float* ws = (float*)d_ws;
    float* h0    = ws;                               // B_*H0_
    float* h1    = h0 + (size_t)B_ * H0_;            // B_*H1_
    float* z     = h1 + (size_t)B_ * H1_;            // B_*D_
    float* quant = z  + (size_t)B_ * D_;             // B_*D_
    float* resid = quant + (size_t)B_ * D_;          // B_*D_
    float* cnorm = resid + (size_t)B_ * D_;          // Q_*K_
    float* loss  = cnorm + (size_t)Q_ * K_;          // 16
    u64*   best  = (u64*)(loss + 16);                // B_
    u16*   p     = (u16*)(best + B_);

    u16* ew0t = p; p += (size_t)3 * IN_ * H0_;
    u16* ew1t = p; p += (size_t)3 * H0_ * H1_;
    u16* ew2t = p; p += (size_t)3 * H1_ * D_;
    u16* dw0t = p; p += (size_t)D_ * H1_;
    u16* dw1t = p; p += (size_t)H1_ * H0_;
    u16* dw2t = p; p += (size_t)H0_ * IN_;
    u16* cbs  = p;                                   // 3 * Q_*K_*D_

    const size_t ew0s = (size_t)IN_ * H0_, ew1s = (size_t)H0_ * H1_,
                 ew2s = (size_t)H1_ * D_, cbsz = (size_t)Q_ * K_ * D_;

    // ---- prepasses: weight transpose+split, codebook split, cnorm ----
    wsplit_kernel<3><<<dim3(H0_ / 32, IN_ / 32), 256, 0, stream>>>(
        e_w0, ew0t, ew0t + ew0s, ew0t + 2 * ew0s, IN_, H0_);
    wsplit_kernel<3><<<dim3(H1_ / 32, H0_ / 32), 256, 0, stream>>>(
        e_w1, ew1t, ew1t + ew1s, ew1t + 2 * ew1s, H0_, H1_);
    wsplit_kernel<3><<<dim3(D_ / 32, H1_ / 32), 256, 0, stream>>>(
        e_w2, ew2t, ew2t + ew2s, ew2t + 2 * ew2s, H1_, D_);
    wsplit_kernel<1><<<dim3(H1_ / 32, D_ / 32), 256, 0, stream>>>(
        d_w0, dw0t, nullptr, nullptr, D_, H1_);
    wsplit_kernel<1><<<dim3(H0_ / 32, H1_ / 32), 256, 0, stream>>>(
        d_w1, dw1t, nullptr, nullptr, H1_, H0_);
    wsplit_kernel<1><<<dim3(IN_ / 32, H0_ / 32), 256, 0, stream>>>(
        d_w2, dw2t, nullptr, nullptr, H0_, IN_);
    cbsplit_kernel<<<(Q_ * K_ * D_ / 4) / 256, 256, 0, stream>>>(
        codebooks, cbs, cbs + cbsz, cbs + 2 * cbsz);
    cnorm_kernel<<<(Q_ * K_) / 4, 256, 0, stream>>>(codebooks, cnorm);

    // ---- encoder (bf16x3 MFMA) ----
    gemm_mfma<3, 1, 0><<<dim3(H0_ / 128, B_ / 128), 256, 0, stream>>>(
        x, ew0t, ew0t + ew0s, ew0t + 2 * ew0s, e_b0, h0, nullptr, B_, H0_, IN_);
    gemm_mfma<3, 1, 0><<<dim3(H1_ / 128, B_ / 128), 256, 0, stream>>>(
        h0, ew1t, ew1t + ew1s, ew1t + 2 * ew1s, e_b1, h1, nullptr, B_, H1_, H0_);
    gemm_mfma<3, 0, 0><<<dim3(D_ / 128, B_ / 128), 256, 0, stream>>>(
        h1, ew2t, ew2t + ew2s, ew2t + 2 * ew2s, e_b2, z, nullptr, B_, D_, H1_);

    // ---- residual VQ ----
    rvq_init_kernel<<<(B_ * D_ / 4) / 256, 256, 0, stream>>>(z, quant, resid, loss);
    for (int q = 0; q < Q_; q++) {
        const float* cb_q = codebooks + (size_t)q * K_ * D_;
        init_best_kernel<<<B_ / 256, 256, 0, stream>>>(best);
        gemm_mfma<3, 0, 1><<<dim3(K_ / 128, B_ / 128), 256, 0, stream>>>(
            resid, cbs + (size_t)q * K_ * D_, cbs + cbsz + (size_t)q * K_ * D_,
            cbs + 2 * cbsz + (size_t)q * K_ * D_,
            cnorm + (size_t)q * K_, nullptr, best, B_, K_, D_);
        vq_update_kernel<<<B_ / 4, 256, 0, stream>>>(
            best, cb_q, resid, quant, out_idx, loss, q);
    }
    loss_write_kernel<<<1, 64, 0, stream>>>(loss, out_loss);

    // ---- decoder (plain bf16 MFMA, NS=1) ----
    gemm_mfma<1, 1, 0><<<dim3(H1_ / 128, B_ / 128), 256, 0, stream>>>(
        quant, dw0t, nullptr, nullptr, d_b0, h1, nullptr, B_, H1_, D_);
    gemm_mfma<1, 1, 0><<<dim3(H0_ / 128, B_ / 128), 256, 0, stream>>>(
        h1, dw1t, nullptr, nullptr, d_b1, h0, nullptr, B_, H0_, H1_);
    gemm_mfma<1, 0, 0><<<dim3(IN_ / 128, B_ / 128), 256, 0, stream>>>(
        h0, dw2t, nullptr, nullptr, d_b2, out_decoded, nullptr, B_, IN_, H0_);
}